// Round 7
// baseline (186.910 us; speedup 1.0000x reference)
//
#include <hip/hip_runtime.h>
#include <hip/hip_bf16.h>
#include <math.h>

// Problem constants (ModernBERT attention)
#define BATCH 4
#define SEQ   2048
#define DMODEL 768
#define NHEADS 12
#define HDIM  64
#define WIN   64          // window each side
#define QKV_LD 2304      // 3*DMODEL

typedef __attribute__((ext_vector_type(8))) short bf16x8;  // 8 bf16 = 4 VGPRs
typedef __attribute__((ext_vector_type(4))) float f32x4;

typedef __attribute__((address_space(1))) const unsigned int guint;
typedef __attribute__((address_space(3))) unsigned int luint;

__device__ inline void gl_lds16(const __hip_bfloat16* g, __hip_bfloat16* l) {
    __builtin_amdgcn_global_load_lds((guint*)g, (luint*)l, 16, 0, 0);
}

__device__ inline void to_out(float* p, float v) { *p = v; }
__device__ inline void to_out(__hip_bfloat16* p, float v) { *p = __float2bfloat16(v); }

// ---------------------------------------------------------------------------
// fused setup: cast hidden/Wqkv/Wo to bf16 + build rope cos/sin table.
// ---------------------------------------------------------------------------
#define N4_HID  (BATCH * SEQ * DMODEL / 4)     // 1,572,864
#define N4_WQKV (QKV_LD * DMODEL / 4)          //   442,368
#define N4_WO   (DMODEL * DMODEL / 4)          //   147,456
#define N_ROPE  (SEQ * 32)                     //    65,536
#define SETUP_TOTAL (N4_HID + N4_WQKV + N4_WO + N_ROPE)

__device__ inline void cast4(const float* in, __hip_bfloat16* out, int i) {
    float4 v = ((const float4*)in)[i];
    union { ushort4 u; __hip_bfloat16 h[4]; } o;
    o.h[0] = __float2bfloat16(v.x); o.h[1] = __float2bfloat16(v.y);
    o.h[2] = __float2bfloat16(v.z); o.h[3] = __float2bfloat16(v.w);
    ((ushort4*)out)[i] = o.u;
}

__global__ __launch_bounds__(256) void setup_kernel(const float* __restrict__ hidden,
                                                    const float* __restrict__ Wqkv,
                                                    const float* __restrict__ Wo,
                                                    __hip_bfloat16* __restrict__ hid_bf,
                                                    __hip_bfloat16* __restrict__ wqkv_bf,
                                                    __hip_bfloat16* __restrict__ wo_bf,
                                                    float2* __restrict__ tab) {
    int id = blockIdx.x * 256 + threadIdx.x;
    if (id < N4_HID) {
        cast4(hidden, hid_bf, id);
    } else if (id < N4_HID + N4_WQKV) {
        cast4(Wqkv, wqkv_bf, id - N4_HID);
    } else if (id < N4_HID + N4_WQKV + N4_WO) {
        cast4(Wo, wo_bf, id - N4_HID - N4_WQKV);
    } else if (id < SETUP_TOTAL) {
        int idx = id - (N4_HID + N4_WQKV + N4_WO);
        int t = idx >> 5, j = idx & 31;
        const float L2T_OVER_32 = 13.287712379549449f / 32.0f;  // log2(10000)/32
        float inv = exp2f(-(float)j * L2T_OVER_32);
        float s, c;
        sincosf((float)t * inv, &s, &c);
        tab[idx] = make_float2(c, s);
    }
}

// ---------------------------------------------------------------------------
// bf16 MFMA NT GEMM: C[m,n] = sum_k A[m*lda+k]*B[n*ldb+k]
// BM=128, BN=64*NWN. BK=32 with DOUBLE-BUFFERED LDS: per iter
//   barrier -> issue async loads for buf^1 -> compute buf
// so the vmcnt drain at the next barrier overlaps a full compute phase
// (single-buffer exposed the whole staging latency every iteration).
// Layout: row stride 64B, source chunk XOR-swizzled (c^(row&3)) -> fragment
// ds_read_b128 bank pattern identical to the R6 layout that measured
// SQ_LDS_BANK_CONFLICT == 0.
// Epilogue: direct per-lane stores, no barriers. XCD-aware 1D grid.
// Optional fused RoPE epilogue on q/k columns (rope_tab != nullptr).
// ---------------------------------------------------------------------------
template <typename OutT, int NWN>
__global__ __launch_bounds__(256) void gemm_nt_bf16(const __hip_bfloat16* __restrict__ A,
                                                    const __hip_bfloat16* __restrict__ B,
                                                    OutT* __restrict__ C,
                                                    int lda, int ldb, int ldc, int K,
                                                    const float2* __restrict__ rope_tab) {
    constexpr int BN  = 64 * NWN;     // 128 or 64
    constexpr int NWM = 4 / NWN;      // 2 or 4
    constexpr int WM  = 128 / NWM;    // 64 or 32
    constexpr int MI  = WM / 16;      // 4 or 2

    __shared__ __align__(16) __hip_bfloat16 As[2][128 * 32];  // 2 x 8 KB
    __shared__ __align__(16) __hip_bfloat16 Bs[2][BN * 32];   // 2 x 8/4 KB

    const int tid  = threadIdx.x;
    const int lane = tid & 63;
    const int wave = tid >> 6;
    const int wm   = wave / NWN;
    const int wn   = wave % NWN;
    const int fr   = lane & 15;
    const int quad = lane >> 4;

    // XCD-aware swizzle (gridM = 64 m-tiles, 8 per XCD)
    const int bid = blockIdx.x;
    const int x   = bid & 7;
    const int j   = bid >> 3;
    const int m0  = (x * 8 + (j & 7)) * 128;
    const int n0  = (j >> 3) * BN;

    f32x4 acc[MI][4];
#pragma unroll
    for (int i = 0; i < MI; i++)
#pragma unroll
        for (int jj = 0; jj < 4; jj++) acc[i][jj] = (f32x4){0.f, 0.f, 0.f, 0.f};

    // stage one BK=32 tile pair into buffer `buf`
    auto stage = [&](int buf, int k0) {
        // A: 128x32 = 512 chunks of 16B; 2 insts/wave
#pragma unroll
        for (int c = 0; c < 2; c++) {
            int t = (wave * 2 + c) * 64 + lane;     // 0..511
            int row = t >> 2, ch = t & 3;
            int gcol = (ch ^ (row & 3)) * 8;
            gl_lds16(A + (size_t)(m0 + row) * lda + k0 + gcol, &As[buf][t * 8]);
        }
        // B: BN x 32 chunks; NWN insts/wave
#pragma unroll
        for (int c = 0; c < NWN; c++) {
            int t = (wave * NWN + c) * 64 + lane;
            int row = t >> 2, ch = t & 3;
            int gcol = (ch ^ (row & 3)) * 8;
            gl_lds16(B + (size_t)(n0 + row) * ldb + k0 + gcol, &Bs[buf][t * 8]);
        }
    };

    const int NIT = K >> 5;   // 24 at K=768
    stage(0, 0);
    for (int i = 0; i < NIT; i++) {
        const int cur = i & 1;
        __syncthreads();                     // drains loads issued last iter (overlapped w/ compute)
        if (i + 1 < NIT) stage(1 - cur, (i + 1) * 32);

        bf16x8 af[MI], bf_[4];
#pragma unroll
        for (int mi = 0; mi < MI; mi++) {
            int row = wm * WM + mi * 16 + fr;
            int pos = quad ^ (row & 3);
            af[mi] = *(const bf16x8*)&As[cur][row * 32 + pos * 8];
        }
#pragma unroll
        for (int ni = 0; ni < 4; ni++) {
            int row = wn * 64 + ni * 16 + fr;
            int pos = quad ^ (row & 3);
            bf_[ni] = *(const bf16x8*)&Bs[cur][row * 32 + pos * 8];
        }
#pragma unroll
        for (int mi = 0; mi < MI; mi++)
#pragma unroll
            for (int ni = 0; ni < 4; ni++)
                acc[mi][ni] = __builtin_amdgcn_mfma_f32_16x16x32_bf16(af[mi], bf_[ni], acc[mi][ni], 0, 0, 0);
    }

    // fused RoPE: 64-col group b0 covers exactly one head; pairs (ni, ni+2)
    const int b0 = n0 + wn * 64;
    if (rope_tab != nullptr && b0 < 2 * DMODEL) {
#pragma unroll
        for (int mi = 0; mi < MI; mi++) {
#pragma unroll
            for (int r = 0; r < 4; r++) {
                int t = (m0 + wm * WM + mi * 16 + quad * 4 + r) & (SEQ - 1);
#pragma unroll
                for (int ni = 0; ni < 2; ni++) {
                    float2 cs = rope_tab[t * 32 + ni * 16 + fr];
                    float x0 = acc[mi][ni][r], x1 = acc[mi][ni + 2][r];
                    acc[mi][ni][r]     = x0 * cs.x - x1 * cs.y;
                    acc[mi][ni + 2][r] = x0 * cs.y + x1 * cs.x;
                }
            }
        }
    }

    // direct scalar-store epilogue (no barriers)
#pragma unroll
    for (int mi = 0; mi < MI; mi++)
#pragma unroll
        for (int ni = 0; ni < 4; ni++) {
            f32x4 v = acc[mi][ni];
            int gc = b0 + ni * 16 + fr;
            size_t rbase = (size_t)(m0 + wm * WM + mi * 16 + quad * 4);
#pragma unroll
            for (int r = 0; r < 4; r++)
                to_out(&C[(rbase + r) * ldc + gc], v[r]);
        }
}

// ---------------------------------------------------------------------------
// Sliding-window attention, one block per (b, head, 64-query tile).
// QK^T and PV via MFMA; in-register softmax via quad-group shuffles.
// Q fragments loaded directly from global. K staged stride 64 + XOR swizzle.
// LDS 48 KB -> 3 blocks/CU.
// ---------------------------------------------------------------------------
#define PLD  192

__global__ __launch_bounds__(256) void attn_kernel(const __hip_bfloat16* __restrict__ qkv,
                                                   const int* __restrict__ mask,
                                                   __hip_bfloat16* __restrict__ attn) {
    __shared__ __align__(16) char smem[49152];
    __hip_bfloat16* Ks = (__hip_bfloat16*)smem;            // [192][64] swizzled
    __hip_bfloat16* Pb = (__hip_bfloat16*)smem;            // [64][192] swizzled (aliases Ks)
    __hip_bfloat16* Vt = (__hip_bfloat16*)(smem + 24576);  // [64][192] swizzled

    const int tid  = threadIdx.x;
    const int lane = tid & 63;
    const int wave = tid >> 6;
    const int fr   = lane & 15;
    const int quad = lane >> 4;

    // XCD-aware swizzle: 1536 blocks = 8 XCDs x 192
    const int bid  = blockIdx.x;
    const int x    = bid & 7;
    const int j    = bid >> 3;                 // 0..191
    const int b    = x >> 1;
    const int q0   = ((x & 1) * 16 + (j & 15)) * 64;
    const int head = j >> 4;                   // 0..11

    const int klo = max(0, q0 - WIN);
    const int khi = min(SEQ, q0 + 64 + WIN);
    const int nk  = khi - klo;     // 128 or 192
    const int nt  = nk >> 4;       // 8 or 12
    const int nkc = nk >> 5;       // 4 or 6

    const size_t rowbase = (size_t)(b * SEQ) * QKV_LD + head * HDIM;

    // ---- stage K [nk][64] XOR-swizzled: up to 1536 uint4 tasks
    for (int task = tid; task < nk * 8; task += 256) {
        int row = task >> 3, g = task & 7;
        uint4 v = *(const uint4*)(qkv + rowbase + (size_t)(klo + row) * QKV_LD + DMODEL + g * 8);
        *(uint4*)(Ks + row * 64 + (g ^ (row & 7)) * 8) = v;
    }
    // ---- stage V transposed [64][nk], XOR-swizzled chunks of 8
    {
        int h = lane;
        const __hip_bfloat16* vb = qkv + rowbase + 2 * DMODEL + h;
        int ng = nk >> 3;
        for (int g = wave; g < ng; g += 4) {
            unsigned int u0, u1, u2, u3;
            {
                unsigned short a0 = *(const unsigned short*)(vb + (size_t)(klo + g * 8 + 0) * QKV_LD);
                unsigned short a1 = *(const unsigned short*)(vb + (size_t)(klo + g * 8 + 1) * QKV_LD);
                unsigned short a2 = *(const unsigned short*)(vb + (size_t)(klo + g * 8 + 2) * QKV_LD);
                unsigned short a3 = *(const unsigned short*)(vb + (size_t)(klo + g * 8 + 3) * QKV_LD);
                unsigned short a4 = *(const unsigned short*)(vb + (size_t)(klo + g * 8 + 4) * QKV_LD);
                unsigned short a5 = *(const unsigned short*)(vb + (size_t)(klo + g * 8 + 5) * QKV_LD);
                unsigned short a6 = *(const unsigned short*)(vb + (size_t)(klo + g * 8 + 6) * QKV_LD);
                unsigned short a7 = *(const unsigned short*)(vb + (size_t)(klo + g * 8 + 7) * QKV_LD);
                u0 = (unsigned int)a0 | ((unsigned int)a1 << 16);
                u1 = (unsigned int)a2 | ((unsigned int)a3 << 16);
                u2 = (unsigned int)a4 | ((unsigned int)a5 << 16);
                u3 = (unsigned int)a6 | ((unsigned int)a7 << 16);
            }
            int cs = g ^ (h & 7);
            *(uint4*)(Vt + h * PLD + cs * 8) = make_uint4(u0, u1, u2, u3);
        }
    }

    // ---- Q fragments direct from global (A-layout: row=fr, k=quad*8+j)
    const int qrow0 = q0 + wave * 16;
    bf16x8 aq0 = *(const bf16x8*)(qkv + rowbase + (size_t)(qrow0 + fr) * QKV_LD + quad * 8);
    bf16x8 aq1 = *(const bf16x8*)(qkv + rowbase + (size_t)(qrow0 + fr) * QKV_LD + 32 + quad * 8);

    const int* mb = mask + b * SEQ;
    int mq[4];
#pragma unroll
    for (int r = 0; r < 4; r++) mq[r] = mb[qrow0 + quad * 4 + r];

    __syncthreads();

    // ---- QK^T via MFMA over key tiles
    f32x4 sc[12];
#pragma unroll
    for (int kt = 0; kt < 12; kt++) sc[kt] = (f32x4){-1e30f, -1e30f, -1e30f, -1e30f};

#pragma unroll
    for (int kt = 0; kt < 12; kt++) {
        if (kt < nt) {
            int krow = kt * 16 + fr;
            int kg = klo + krow;
            int p0 = (quad) ^ (krow & 7);
            int p1 = (4 + quad) ^ (krow & 7);
            bf16x8 bk0 = *(const bf16x8*)(Ks + krow * 64 + p0 * 8);
            bf16x8 bk1 = *(const bf16x8*)(Ks + krow * 64 + p1 * 8);
            f32x4 a = (f32x4){0.f, 0.f, 0.f, 0.f};
            a = __builtin_amdgcn_mfma_f32_16x16x32_bf16(aq0, bk0, a, 0, 0, 0);
            a = __builtin_amdgcn_mfma_f32_16x16x32_bf16(aq1, bk1, a, 0, 0, 0);
            int mk = mb[kg];
            f32x4 s;
#pragma unroll
            for (int r = 0; r < 4; r++) {
                int qg = qrow0 + quad * 4 + r;
                bool ok = (abs(qg - kg) <= WIN) && (mk != 0) && (mq[r] != 0);
                s[r] = ok ? a[r] * 0.125f : -1e30f;
            }
            sc[kt] = s;
        }
    }

    // ---- in-register softmax: reduce across fr lanes (same quad group)
    f32x4 mx = sc[0];
#pragma unroll
    for (int kt = 1; kt < 12; kt++)
#pragma unroll
        for (int r = 0; r < 4; r++) mx[r] = fmaxf(mx[r], sc[kt][r]);
#pragma unroll
    for (int off = 8; off >= 1; off >>= 1)
#pragma unroll
        for (int r = 0; r < 4; r++) mx[r] = fmaxf(mx[r], __shfl_xor(mx[r], off));

    f32x4 sum = (f32x4){0.f, 0.f, 0.f, 0.f};
#pragma unroll
    for (int kt = 0; kt < 12; kt++)
#pragma unroll
        for (int r = 0; r < 4; r++) {
            float e = __expf(sc[kt][r] - mx[r]);
            sc[kt][r] = e;
            sum[r] += e;
        }
#pragma unroll
    for (int off = 8; off >= 1; off >>= 1)
#pragma unroll
        for (int r = 0; r < 4; r++) sum[r] += __shfl_xor(sum[r], off);
    f32x4 rs;
#pragma unroll
    for (int r = 0; r < 4; r++) rs[r] = 1.0f / sum[r];

    // ---- write P (bf16, A-layout-friendly, swizzled) into Ks space
    __syncthreads();   // all waves done reading Ks
#pragma unroll
    for (int kt = 0; kt < 12; kt++) {
        if (kt < nt) {
#pragma unroll
            for (int r = 0; r < 4; r++) {
                int prow = wave * 16 + quad * 4 + r;
                int c = kt * 2 + (fr >> 3);
                int cs = c ^ (prow & 7);
                Pb[prow * PLD + cs * 8 + (fr & 7)] = __float2bfloat16(sc[kt][r] * rs[r]);
            }
        }
    }
    __syncthreads();

    // ---- PV via MFMA: O[16q][64h] per wave
    f32x4 o[4];
#pragma unroll
    for (int ht = 0; ht < 4; ht++) o[ht] = (f32x4){0.f, 0.f, 0.f, 0.f};

#pragma unroll
    for (int kc = 0; kc < 6; kc++) {
        if (kc < nkc) {
            int cs = (kc * 4 + quad) ^ (fr & 7);
            bf16x8 ap = *(const bf16x8*)(Pb + (wave * 16 + fr) * PLD + cs * 8);
#pragma unroll
            for (int ht = 0; ht < 4; ht++) {
                bf16x8 bv = *(const bf16x8*)(Vt + (ht * 16 + fr) * PLD + cs * 8);
                o[ht] = __builtin_amdgcn_mfma_f32_16x16x32_bf16(ap, bv, o[ht], 0, 0, 0);
            }
        }
    }

    // ---- store O (bf16) to attn [B*T, 768]
    __hip_bfloat16* ob = attn + (size_t)(b * SEQ + qrow0) * DMODEL + head * HDIM;
#pragma unroll
    for (int r = 0; r < 4; r++)
#pragma unroll
        for (int ht = 0; ht < 4; ht++)
            ob[(size_t)(quad * 4 + r) * DMODEL + ht * 16 + fr] = __float2bfloat16(o[ht][r]);
}

// ---------------------------------------------------------------------------
extern "C" void kernel_launch(void* const* d_in, const int* in_sizes, int n_in,
                              void* d_out, int out_size, void* d_ws, size_t ws_size,
                              hipStream_t stream) {
    const float* hidden = (const float*)d_in[0];
    const int*   mask   = (const int*)d_in[1];
    const float* Wqkv   = (const float*)d_in[2];
    const float* Wo     = (const float*)d_in[3];
    float* out = (float*)d_out;

    char* w = (char*)d_ws;
    __hip_bfloat16* qkv_bf  = (__hip_bfloat16*)(w);              // 37,748,736
    __hip_bfloat16* hid_bf  = (__hip_bfloat16*)(w + 37748736);   // 12,582,912
    __hip_bfloat16* wqkv_bf = (__hip_bfloat16*)(w + 50331648);   //  3,538,944
    __hip_bfloat16* wo_bf   = (__hip_bfloat16*)(w + 53870592);   //  1,179,648
    __hip_bfloat16* attn_bf = (__hip_bfloat16*)(w + 55050240);   // 12,582,912
    float2*         tab     = (float2*)(w + 67633152);           //    524,288

    // 0) fused setup: casts + rope table (one launch)
    setup_kernel<<<SETUP_TOTAL / 256, 256, 0, stream>>>(hidden, Wqkv, Wo,
                                                        hid_bf, wqkv_bf, wo_bf, tab);

    // 1) QKV projection + fused RoPE (128x128 tiles, 18 n-tiles x 64 m-tiles)
    gemm_nt_bf16<__hip_bfloat16, 2><<<18 * 64, 256, 0, stream>>>(hid_bf, wqkv_bf, qkv_bf,
                                                                 DMODEL, DMODEL, QKV_LD, DMODEL, tab);

    // 2) sliding-window attention (XCD-swizzled 1D grid)
    attn_kernel<<<(SEQ / 64) * NHEADS * BATCH, 256, 0, stream>>>(qkv_bf, mask, attn_bf);

    // 3) output projection (128x64 tiles -> 768 blocks = 3 blocks/CU)
    gemm_nt_bf16<float, 1><<<12 * 64, 256, 0, stream>>>(attn_bf, wo_bf, out,
                                                        DMODEL, DMODEL, DMODEL, DMODEL, nullptr);
}

// Round 8
// 186.795 us; speedup vs baseline: 1.0006x; 1.0006x over previous
//
#include <hip/hip_runtime.h>
#include <hip/hip_bf16.h>
#include <math.h>

// Problem constants (ModernBERT attention)
#define BATCH 4
#define SEQ   2048
#define DMODEL 768
#define NHEADS 12
#define HDIM  64
#define WIN   64          // window each side
#define QKV_LD 2304      // 3*DMODEL

typedef __attribute__((ext_vector_type(8))) short bf16x8;  // 8 bf16 = 4 VGPRs
typedef __attribute__((ext_vector_type(4))) float f32x4;

typedef __attribute__((address_space(1))) const unsigned int guint;
typedef __attribute__((address_space(3))) unsigned int luint;

__device__ inline void gl_lds16(const __hip_bfloat16* g, __hip_bfloat16* l) {
    __builtin_amdgcn_global_load_lds((guint*)g, (luint*)l, 16, 0, 0);
}

__device__ inline void to_out(float* p, float v) { *p = v; }
__device__ inline void to_out(__hip_bfloat16* p, float v) { *p = __float2bfloat16(v); }

// ---------------------------------------------------------------------------
// fused setup: cast hidden/Wqkv/Wo to bf16 + build rope cos/sin table.
// ---------------------------------------------------------------------------
#define N4_HID  (BATCH * SEQ * DMODEL / 4)     // 1,572,864
#define N4_WQKV (QKV_LD * DMODEL / 4)          //   442,368
#define N4_WO   (DMODEL * DMODEL / 4)          //   147,456
#define N_ROPE  (SEQ * 32)                     //    65,536
#define SETUP_TOTAL (N4_HID + N4_WQKV + N4_WO + N_ROPE)

__device__ inline void cast4(const float* in, __hip_bfloat16* out, int i) {
    float4 v = ((const float4*)in)[i];
    union { ushort4 u; __hip_bfloat16 h[4]; } o;
    o.h[0] = __float2bfloat16(v.x); o.h[1] = __float2bfloat16(v.y);
    o.h[2] = __float2bfloat16(v.z); o.h[3] = __float2bfloat16(v.w);
    ((ushort4*)out)[i] = o.u;
}

__global__ __launch_bounds__(256) void setup_kernel(const float* __restrict__ hidden,
                                                    const float* __restrict__ Wqkv,
                                                    const float* __restrict__ Wo,
                                                    __hip_bfloat16* __restrict__ hid_bf,
                                                    __hip_bfloat16* __restrict__ wqkv_bf,
                                                    __hip_bfloat16* __restrict__ wo_bf,
                                                    float2* __restrict__ tab) {
    int id = blockIdx.x * 256 + threadIdx.x;
    if (id < N4_HID) {
        cast4(hidden, hid_bf, id);
    } else if (id < N4_HID + N4_WQKV) {
        cast4(Wqkv, wqkv_bf, id - N4_HID);
    } else if (id < N4_HID + N4_WQKV + N4_WO) {
        cast4(Wo, wo_bf, id - N4_HID - N4_WQKV);
    } else if (id < SETUP_TOTAL) {
        int idx = id - (N4_HID + N4_WQKV + N4_WO);
        int t = idx >> 5, j = idx & 31;
        const float L2T_OVER_32 = 13.287712379549449f / 32.0f;  // log2(10000)/32
        float inv = exp2f(-(float)j * L2T_OVER_32);
        float s, c;
        sincosf((float)t * inv, &s, &c);
        tab[idx] = make_float2(c, s);
    }
}

// ---------------------------------------------------------------------------
// bf16 MFMA NT GEMM: C[m,n] = sum_k A[m*lda+k]*B[n*ldb+k]
// BM=128, BN=64*NWN. BK=32, DOUBLE-BUFFERED LDS: per iter
//   barrier -> issue async loads for buf^1 -> compute buf.
// Swizzle FIX vs R7: pos = quad ^ ((row>>1)&3). With 64B row stride the bank
// phase is (row%2)*16 + pos*4; consecutive even rows now cycle pos 0..3, so
// each 4-bank group gets exactly 2 lanes -> 2-way, free (R7's quad^(row&3)
// gave rows {0,4,8,12} identical pos -> 4-way, 3.5M conflict cycles).
// Epilogue: direct per-lane stores, no barriers. XCD-aware 1D grid.
// Optional fused RoPE epilogue on q/k columns (rope_tab != nullptr).
// ---------------------------------------------------------------------------
template <typename OutT, int NWN>
__global__ __launch_bounds__(256) void gemm_nt_bf16(const __hip_bfloat16* __restrict__ A,
                                                    const __hip_bfloat16* __restrict__ B,
                                                    OutT* __restrict__ C,
                                                    int lda, int ldb, int ldc, int K,
                                                    const float2* __restrict__ rope_tab) {
    constexpr int BN  = 64 * NWN;     // 128 or 64
    constexpr int NWM = 4 / NWN;      // 2 or 4
    constexpr int WM  = 128 / NWM;    // 64 or 32
    constexpr int MI  = WM / 16;      // 4 or 2

    __shared__ __align__(16) __hip_bfloat16 As[2][128 * 32];  // 2 x 8 KB
    __shared__ __align__(16) __hip_bfloat16 Bs[2][BN * 32];   // 2 x 8/4 KB

    const int tid  = threadIdx.x;
    const int lane = tid & 63;
    const int wave = tid >> 6;
    const int wm   = wave / NWN;
    const int wn   = wave % NWN;
    const int fr   = lane & 15;
    const int quad = lane >> 4;

    // XCD-aware swizzle (gridM = 64 m-tiles, 8 per XCD)
    const int bid = blockIdx.x;
    const int x   = bid & 7;
    const int j   = bid >> 3;
    const int m0  = (x * 8 + (j & 7)) * 128;
    const int n0  = (j >> 3) * BN;

    f32x4 acc[MI][4];
#pragma unroll
    for (int i = 0; i < MI; i++)
#pragma unroll
        for (int jj = 0; jj < 4; jj++) acc[i][jj] = (f32x4){0.f, 0.f, 0.f, 0.f};

    // stage one BK=32 tile pair into buffer `buf`
    auto stage = [&](int buf, int k0) {
        // A: 128x32 = 512 chunks of 16B; 2 insts/wave
#pragma unroll
        for (int c = 0; c < 2; c++) {
            int t = (wave * 2 + c) * 64 + lane;     // 0..511
            int row = t >> 2, ch = t & 3;
            int gcol = (ch ^ ((row >> 1) & 3)) * 8;
            gl_lds16(A + (size_t)(m0 + row) * lda + k0 + gcol, &As[buf][t * 8]);
        }
        // B: BN x 32 chunks; NWN insts/wave
#pragma unroll
        for (int c = 0; c < NWN; c++) {
            int t = (wave * NWN + c) * 64 + lane;
            int row = t >> 2, ch = t & 3;
            int gcol = (ch ^ ((row >> 1) & 3)) * 8;
            gl_lds16(B + (size_t)(n0 + row) * ldb + k0 + gcol, &Bs[buf][t * 8]);
        }
    };

    const int NIT = K >> 5;   // 24 at K=768
    stage(0, 0);
    for (int i = 0; i < NIT; i++) {
        const int cur = i & 1;
        __syncthreads();                     // drains loads issued last iter (overlapped w/ compute)
        if (i + 1 < NIT) stage(1 - cur, (i + 1) * 32);

        bf16x8 af[MI], bf_[4];
#pragma unroll
        for (int mi = 0; mi < MI; mi++) {
            int row = wm * WM + mi * 16 + fr;
            int pos = quad ^ ((row >> 1) & 3);
            af[mi] = *(const bf16x8*)&As[cur][row * 32 + pos * 8];
        }
#pragma unroll
        for (int ni = 0; ni < 4; ni++) {
            int row = wn * 64 + ni * 16 + fr;
            int pos = quad ^ ((row >> 1) & 3);
            bf_[ni] = *(const bf16x8*)&Bs[cur][row * 32 + pos * 8];
        }
#pragma unroll
        for (int mi = 0; mi < MI; mi++)
#pragma unroll
            for (int ni = 0; ni < 4; ni++)
                acc[mi][ni] = __builtin_amdgcn_mfma_f32_16x16x32_bf16(af[mi], bf_[ni], acc[mi][ni], 0, 0, 0);
    }

    // fused RoPE: 64-col group b0 covers exactly one head; pairs (ni, ni+2)
    const int b0 = n0 + wn * 64;
    if (rope_tab != nullptr && b0 < 2 * DMODEL) {
#pragma unroll
        for (int mi = 0; mi < MI; mi++) {
#pragma unroll
            for (int r = 0; r < 4; r++) {
                int t = (m0 + wm * WM + mi * 16 + quad * 4 + r) & (SEQ - 1);
#pragma unroll
                for (int ni = 0; ni < 2; ni++) {
                    float2 cs = rope_tab[t * 32 + ni * 16 + fr];
                    float x0 = acc[mi][ni][r], x1 = acc[mi][ni + 2][r];
                    acc[mi][ni][r]     = x0 * cs.x - x1 * cs.y;
                    acc[mi][ni + 2][r] = x0 * cs.y + x1 * cs.x;
                }
            }
        }
    }

    // direct scalar-store epilogue (no barriers)
#pragma unroll
    for (int mi = 0; mi < MI; mi++)
#pragma unroll
        for (int ni = 0; ni < 4; ni++) {
            f32x4 v = acc[mi][ni];
            int gc = b0 + ni * 16 + fr;
            size_t rbase = (size_t)(m0 + wm * WM + mi * 16 + quad * 4);
#pragma unroll
            for (int r = 0; r < 4; r++)
                to_out(&C[(rbase + r) * ldc + gc], v[r]);
        }
}

// ---------------------------------------------------------------------------
// Sliding-window attention, one block per (b, head, 64-query tile).
// QK^T and PV via MFMA; in-register softmax via quad-group shuffles.
// Q fragments loaded directly from global. K staged stride 64 + XOR swizzle.
// LDS 48 KB -> 3 blocks/CU.
// ---------------------------------------------------------------------------
#define PLD  192

__global__ __launch_bounds__(256) void attn_kernel(const __hip_bfloat16* __restrict__ qkv,
                                                   const int* __restrict__ mask,
                                                   __hip_bfloat16* __restrict__ attn) {
    __shared__ __align__(16) char smem[49152];
    __hip_bfloat16* Ks = (__hip_bfloat16*)smem;            // [192][64] swizzled
    __hip_bfloat16* Pb = (__hip_bfloat16*)smem;            // [64][192] swizzled (aliases Ks)
    __hip_bfloat16* Vt = (__hip_bfloat16*)(smem + 24576);  // [64][192] swizzled

    const int tid  = threadIdx.x;
    const int lane = tid & 63;
    const int wave = tid >> 6;
    const int fr   = lane & 15;
    const int quad = lane >> 4;

    // XCD-aware swizzle: 1536 blocks = 8 XCDs x 192
    const int bid  = blockIdx.x;
    const int x    = bid & 7;
    const int j    = bid >> 3;                 // 0..191
    const int b    = x >> 1;
    const int q0   = ((x & 1) * 16 + (j & 15)) * 64;
    const int head = j >> 4;                   // 0..11

    const int klo = max(0, q0 - WIN);
    const int khi = min(SEQ, q0 + 64 + WIN);
    const int nk  = khi - klo;     // 128 or 192
    const int nt  = nk >> 4;       // 8 or 12
    const int nkc = nk >> 5;       // 4 or 6

    const size_t rowbase = (size_t)(b * SEQ) * QKV_LD + head * HDIM;

    // ---- stage K [nk][64] XOR-swizzled: up to 1536 uint4 tasks
    for (int task = tid; task < nk * 8; task += 256) {
        int row = task >> 3, g = task & 7;
        uint4 v = *(const uint4*)(qkv + rowbase + (size_t)(klo + row) * QKV_LD + DMODEL + g * 8);
        *(uint4*)(Ks + row * 64 + (g ^ (row & 7)) * 8) = v;
    }
    // ---- stage V transposed [64][nk], XOR-swizzled chunks of 8
    {
        int h = lane;
        const __hip_bfloat16* vb = qkv + rowbase + 2 * DMODEL + h;
        int ng = nk >> 3;
        for (int g = wave; g < ng; g += 4) {
            unsigned int u0, u1, u2, u3;
            {
                unsigned short a0 = *(const unsigned short*)(vb + (size_t)(klo + g * 8 + 0) * QKV_LD);
                unsigned short a1 = *(const unsigned short*)(vb + (size_t)(klo + g * 8 + 1) * QKV_LD);
                unsigned short a2 = *(const unsigned short*)(vb + (size_t)(klo + g * 8 + 2) * QKV_LD);
                unsigned short a3 = *(const unsigned short*)(vb + (size_t)(klo + g * 8 + 3) * QKV_LD);
                unsigned short a4 = *(const unsigned short*)(vb + (size_t)(klo + g * 8 + 4) * QKV_LD);
                unsigned short a5 = *(const unsigned short*)(vb + (size_t)(klo + g * 8 + 5) * QKV_LD);
                unsigned short a6 = *(const unsigned short*)(vb + (size_t)(klo + g * 8 + 6) * QKV_LD);
                unsigned short a7 = *(const unsigned short*)(vb + (size_t)(klo + g * 8 + 7) * QKV_LD);
                u0 = (unsigned int)a0 | ((unsigned int)a1 << 16);
                u1 = (unsigned int)a2 | ((unsigned int)a3 << 16);
                u2 = (unsigned int)a4 | ((unsigned int)a5 << 16);
                u3 = (unsigned int)a6 | ((unsigned int)a7 << 16);
            }
            int cs = g ^ (h & 7);
            *(uint4*)(Vt + h * PLD + cs * 8) = make_uint4(u0, u1, u2, u3);
        }
    }

    // ---- Q fragments direct from global (A-layout: row=fr, k=quad*8+j)
    const int qrow0 = q0 + wave * 16;
    bf16x8 aq0 = *(const bf16x8*)(qkv + rowbase + (size_t)(qrow0 + fr) * QKV_LD + quad * 8);
    bf16x8 aq1 = *(const bf16x8*)(qkv + rowbase + (size_t)(qrow0 + fr) * QKV_LD + 32 + quad * 8);

    const int* mb = mask + b * SEQ;
    int mq[4];
#pragma unroll
    for (int r = 0; r < 4; r++) mq[r] = mb[qrow0 + quad * 4 + r];

    __syncthreads();

    // ---- QK^T via MFMA over key tiles
    f32x4 sc[12];
#pragma unroll
    for (int kt = 0; kt < 12; kt++) sc[kt] = (f32x4){-1e30f, -1e30f, -1e30f, -1e30f};

#pragma unroll
    for (int kt = 0; kt < 12; kt++) {
        if (kt < nt) {
            int krow = kt * 16 + fr;
            int kg = klo + krow;
            int p0 = (quad) ^ (krow & 7);
            int p1 = (4 + quad) ^ (krow & 7);
            bf16x8 bk0 = *(const bf16x8*)(Ks + krow * 64 + p0 * 8);
            bf16x8 bk1 = *(const bf16x8*)(Ks + krow * 64 + p1 * 8);
            f32x4 a = (f32x4){0.f, 0.f, 0.f, 0.f};
            a = __builtin_amdgcn_mfma_f32_16x16x32_bf16(aq0, bk0, a, 0, 0, 0);
            a = __builtin_amdgcn_mfma_f32_16x16x32_bf16(aq1, bk1, a, 0, 0, 0);
            int mk = mb[kg];
            f32x4 s;
#pragma unroll
            for (int r = 0; r < 4; r++) {
                int qg = qrow0 + quad * 4 + r;
                bool ok = (abs(qg - kg) <= WIN) && (mk != 0) && (mq[r] != 0);
                s[r] = ok ? a[r] * 0.125f : -1e30f;
            }
            sc[kt] = s;
        }
    }

    // ---- in-register softmax: reduce across fr lanes (same quad group)
    f32x4 mx = sc[0];
#pragma unroll
    for (int kt = 1; kt < 12; kt++)
#pragma unroll
        for (int r = 0; r < 4; r++) mx[r] = fmaxf(mx[r], sc[kt][r]);
#pragma unroll
    for (int off = 8; off >= 1; off >>= 1)
#pragma unroll
        for (int r = 0; r < 4; r++) mx[r] = fmaxf(mx[r], __shfl_xor(mx[r], off));

    f32x4 sum = (f32x4){0.f, 0.f, 0.f, 0.f};
#pragma unroll
    for (int kt = 0; kt < 12; kt++)
#pragma unroll
        for (int r = 0; r < 4; r++) {
            float e = __expf(sc[kt][r] - mx[r]);
            sc[kt][r] = e;
            sum[r] += e;
        }
#pragma unroll
    for (int off = 8; off >= 1; off >>= 1)
#pragma unroll
        for (int r = 0; r < 4; r++) sum[r] += __shfl_xor(sum[r], off);
    f32x4 rs;
#pragma unroll
    for (int r = 0; r < 4; r++) rs[r] = 1.0f / sum[r];

    // ---- write P (bf16, A-layout-friendly, swizzled) into Ks space
    __syncthreads();   // all waves done reading Ks
#pragma unroll
    for (int kt = 0; kt < 12; kt++) {
        if (kt < nt) {
#pragma unroll
            for (int r = 0; r < 4; r++) {
                int prow = wave * 16 + quad * 4 + r;
                int c = kt * 2 + (fr >> 3);
                int cs = c ^ (prow & 7);
                Pb[prow * PLD + cs * 8 + (fr & 7)] = __float2bfloat16(sc[kt][r] * rs[r]);
            }
        }
    }
    __syncthreads();

    // ---- PV via MFMA: O[16q][64h] per wave
    f32x4 o[4];
#pragma unroll
    for (int ht = 0; ht < 4; ht++) o[ht] = (f32x4){0.f, 0.f, 0.f, 0.f};

#pragma unroll
    for (int kc = 0; kc < 6; kc++) {
        if (kc < nkc) {
            int cs = (kc * 4 + quad) ^ (fr & 7);
            bf16x8 ap = *(const bf16x8*)(Pb + (wave * 16 + fr) * PLD + cs * 8);
#pragma unroll
            for (int ht = 0; ht < 4; ht++) {
                bf16x8 bv = *(const bf16x8*)(Vt + (ht * 16 + fr) * PLD + cs * 8);
                o[ht] = __builtin_amdgcn_mfma_f32_16x16x32_bf16(ap, bv, o[ht], 0, 0, 0);
            }
        }
    }

    // ---- store O (bf16) to attn [B*T, 768]
    __hip_bfloat16* ob = attn + (size_t)(b * SEQ + qrow0) * DMODEL + head * HDIM;
#pragma unroll
    for (int r = 0; r < 4; r++)
#pragma unroll
        for (int ht = 0; ht < 4; ht++)
            ob[(size_t)(quad * 4 + r) * DMODEL + ht * 16 + fr] = __float2bfloat16(o[ht][r]);
}

// ---------------------------------------------------------------------------
extern "C" void kernel_launch(void* const* d_in, const int* in_sizes, int n_in,
                              void* d_out, int out_size, void* d_ws, size_t ws_size,
                              hipStream_t stream) {
    const float* hidden = (const float*)d_in[0];
    const int*   mask   = (const int*)d_in[1];
    const float* Wqkv   = (const float*)d_in[2];
    const float* Wo     = (const float*)d_in[3];
    float* out = (float*)d_out;

    char* w = (char*)d_ws;
    __hip_bfloat16* qkv_bf  = (__hip_bfloat16*)(w);              // 37,748,736
    __hip_bfloat16* hid_bf  = (__hip_bfloat16*)(w + 37748736);   // 12,582,912
    __hip_bfloat16* wqkv_bf = (__hip_bfloat16*)(w + 50331648);   //  3,538,944
    __hip_bfloat16* wo_bf   = (__hip_bfloat16*)(w + 53870592);   //  1,179,648
    __hip_bfloat16* attn_bf = (__hip_bfloat16*)(w + 55050240);   // 12,582,912
    float2*         tab     = (float2*)(w + 67633152);           //    524,288

    // 0) fused setup: casts + rope table (one launch)
    setup_kernel<<<SETUP_TOTAL / 256, 256, 0, stream>>>(hidden, Wqkv, Wo,
                                                        hid_bf, wqkv_bf, wo_bf, tab);

    // 1) QKV projection + fused RoPE (128x128 tiles, 18 n-tiles x 64 m-tiles)
    gemm_nt_bf16<__hip_bfloat16, 2><<<18 * 64, 256, 0, stream>>>(hid_bf, wqkv_bf, qkv_bf,
                                                                 DMODEL, DMODEL, QKV_LD, DMODEL, tab);

    // 2) sliding-window attention (XCD-swizzled 1D grid)
    attn_kernel<<<(SEQ / 64) * NHEADS * BATCH, 256, 0, stream>>>(qkv_bf, mask, attn_bf);

    // 3) output projection (128x64 tiles -> 768 blocks = 3 blocks/CU)
    gemm_nt_bf16<float, 1><<<12 * 64, 256, 0, stream>>>(attn_bf, wo_bf, out,
                                                        DMODEL, DMODEL, DMODEL, DMODEL, nullptr);
}